// Round 7
// baseline (124.562 us; speedup 1.0000x reference)
//
#include <hip/hip_runtime.h>
#include <hip/hip_bf16.h>

#define N_ATOMS 262144
#define NGRAPH  2048
#define INV_SCALE 0.17677669529663687f  // 1/sqrt(32)

typedef float f32x2 __attribute__((ext_vector_type(2)));
typedef float f32x4 __attribute__((ext_vector_type(4)));
typedef short s16x8 __attribute__((ext_vector_type(8)));
typedef unsigned int u32;
typedef unsigned short ushort_t;

// packed fp32 fma with scalar broadcast from LOW/HIGH half of a (R5-verified)
__device__ __forceinline__ f32x2 pk_fma_blo(f32x2 a, f32x2 b, f32x2 c) {
  f32x2 d; asm("v_pk_fma_f32 %0, %1, %2, %3 op_sel_hi:[0,1,1]"
               : "=v"(d) : "v"(a), "v"(b), "v"(c)); return d;
}
__device__ __forceinline__ f32x2 pk_fma_bhi(f32x2 a, f32x2 b, f32x2 c) {
  f32x2 d; asm("v_pk_fma_f32 %0, %1, %2, %3 op_sel:[1,0,0]"
               : "=v"(d) : "v"(a), "v"(b), "v"(c)); return d;
}
__device__ __forceinline__ u32 cvt2_bf16(float lo, float hi) {
  u32 d; asm("v_cvt_pk_bf16_f32 %0, %1, %2" : "=v"(d) : "v"(lo), "v"(hi)); return d;
}

// ---------------- K1: P[h][i] = sum_d Wk[i][h*32+d]*q[h][d]; also bf16 copy.
__global__ void k_prep(const float* __restrict__ Wk, const float* __restrict__ bk,
                       const float* __restrict__ q, float* __restrict__ P,
                       ushort_t* __restrict__ Pbf, float* __restrict__ c) {
  int h = blockIdx.x, i = threadIdx.x;
  float s = 0.f;
  #pragma unroll
  for (int d = 0; d < 32; ++d)
    s = fmaf(Wk[i * 256 + h * 32 + d], q[h * 32 + d], s);
  P[h * 256 + i] = s;
  __hip_bfloat16 hb = __float2bfloat16(s);
  Pbf[h * 256 + i] = *reinterpret_cast<ushort_t*>(&hb);
  if (i == 0) {
    float cc = 0.f;
    #pragma unroll
    for (int d = 0; d < 32; ++d) cc = fmaf(bk[h * 32 + d], q[h * 32 + d], cc);
    c[h] = cc;
  }
}

// ---------------- K1b: segment bounds via one binary search per graph.
__global__ void k_bounds(const int* __restrict__ batch, int* __restrict__ bounds) {
  int g = blockIdx.x * blockDim.x + threadIdx.x;
  if (g >= NGRAPH) return;
  int lo = 0, hi = N_ATOMS;
  while (lo < hi) {
    int mid = (lo + hi) >> 1;
    if (batch[mid] < g) lo = mid + 1; else hi = mid;
  }
  bounds[2 * g] = lo;
  if (g > 0) bounds[2 * g - 1] = lo;
  if (g == NGRAPH - 1) bounds[2 * g + 1] = N_ATOMS;
}

// ---------------- K2: fused scores (bf16 MFMA, A-frags direct from global)
// + exp + exact-fp32 accumulate (R5-verified math).
// One block per graph, 4 waves, wave owns 16-atom chunks at stride 64.
// No LDS staging: lane builds its A-frag by loading x[cb+(lane&15)] rows in
// 32B segments per kt (rows fully consumed across kt -> full line use; the
// fp32 accumulate re-reads the same lines from L1/L2).
__global__ __launch_bounds__(256) void k_fused(const float* __restrict__ x,
                                               const ushort_t* __restrict__ Pbf,
                                               const float* __restrict__ c,
                                               const int* __restrict__ bounds,
                                               float* __restrict__ Ag) {
  int b = blockIdx.x;
  int seg_s = bounds[2 * b], seg_e = bounds[2 * b + 1];
  int t = threadIdx.x, lane = t & 63, wv = t >> 6;
  int hq = lane & 15;   // A-row (atom-in-chunk) AND C-col (head, 8-15 dup)
  int qq = lane >> 4;   // k-quarter / C row-quarter

  __shared__ float As[4][8][256];   // 32 KB epilogue partials
  __shared__ float etab[4][16][8];  // per-wave e-table (fp32), 2 KB
  __shared__ float dws[4][8];
  __shared__ float dinvs[8];

  // Hoist B-frags: B[k = kt*32 + qq*8 + j][col=head] (R6-verified layout)
  s16x8 bfrag[8];
  #pragma unroll
  for (int kt = 0; kt < 8; ++kt)
    bfrag[kt] = *reinterpret_cast<const s16x8*>(Pbf + (hq & 7) * 256 + kt * 32 + qq * 8);
  float cl = c[hq & 7];

  f32x2 A2[8][2];
  #pragma unroll
  for (int k = 0; k < 8; ++k) { A2[k][0] = (f32x2)0.f; A2[k][1] = (f32x2)0.f; }
  float dacc = 0.f;

  for (int cb = seg_s + 16 * wv; cb < seg_e; cb += 64) {
    // ---- scores[atom, head] via 8 chained MFMAs, A-frag straight from global
    int arow = cb + hq; arow = arow < seg_e ? arow : seg_e - 1;
    const float* xr = x + (size_t)arow * 256 + qq * 8;
    f32x4 acc = {0.f, 0.f, 0.f, 0.f};
    #pragma unroll
    for (int kt = 0; kt < 8; ++kt) {
      f32x4 lo = *reinterpret_cast<const f32x4*>(xr + kt * 32);
      f32x4 hi = *reinterpret_cast<const f32x4*>(xr + kt * 32 + 4);
      u32 w[4];
      w[0] = cvt2_bf16(lo[0], lo[1]);
      w[1] = cvt2_bf16(lo[2], lo[3]);
      w[2] = cvt2_bf16(hi[0], hi[1]);
      w[3] = cvt2_bf16(hi[2], hi[3]);
      s16x8 af = *reinterpret_cast<s16x8*>(w);
      acc = __builtin_amdgcn_mfma_f32_16x16x32_bf16(af, bfrag[kt], acc, 0, 0, 0);
    }
    // ---- exp + tail mask + e-table + denominator (C row=qq*4+j, col=hq)
    float ptile = 0.f;
    float ev[4];
    #pragma unroll
    for (int j = 0; j < 4; ++j) {
      int aj = cb + qq * 4 + j;
      float sc = (acc[j] + cl) * INV_SCALE;
      float ee = __expf(sc);
      ee = (aj < seg_e) ? ee : 0.f;
      ev[j] = ee;
      ptile += ee;
    }
    ptile += __shfl_xor(ptile, 16, 64);
    ptile += __shfl_xor(ptile, 32, 64);
    dacc += ptile;
    if (hq < 8) {
      #pragma unroll
      for (int j = 0; j < 4; ++j) etab[wv][qq * 4 + j][hq] = ev[j];
    }
    // ---- exact fp32 accumulate (R5-verified), rows re-read (L1/L2-hot)
    #pragma unroll
    for (int a = 0; a < 16; a += 2) {
      int n0 = cb + a;     n0 = n0 < seg_e ? n0 : seg_e - 1;
      int n1 = cb + a + 1; n1 = n1 < seg_e ? n1 : seg_e - 1;
      f32x4 x0 = *reinterpret_cast<const f32x4*>(x + (size_t)n0 * 256 + 4 * lane);
      f32x4 x1 = *reinterpret_cast<const f32x4*>(x + (size_t)n1 * 256 + 4 * lane);
      f32x4 eA0 = *reinterpret_cast<const f32x4*>(&etab[wv][a][0]);
      f32x4 eA1 = *reinterpret_cast<const f32x4*>(&etab[wv][a][4]);
      f32x4 eB0 = *reinterpret_cast<const f32x4*>(&etab[wv][a + 1][0]);
      f32x4 eB1 = *reinterpret_cast<const f32x4*>(&etab[wv][a + 1][4]);
      f32x2 x0lo = __builtin_shufflevector(x0, x0, 0, 1);
      f32x2 x0hi = __builtin_shufflevector(x0, x0, 2, 3);
      f32x2 x1lo = __builtin_shufflevector(x1, x1, 0, 1);
      f32x2 x1hi = __builtin_shufflevector(x1, x1, 2, 3);
      f32x2 ea[4] = { __builtin_shufflevector(eA0, eA0, 0, 1),
                      __builtin_shufflevector(eA0, eA0, 2, 3),
                      __builtin_shufflevector(eA1, eA1, 0, 1),
                      __builtin_shufflevector(eA1, eA1, 2, 3) };
      f32x2 eb[4] = { __builtin_shufflevector(eB0, eB0, 0, 1),
                      __builtin_shufflevector(eB0, eB0, 2, 3),
                      __builtin_shufflevector(eB1, eB1, 0, 1),
                      __builtin_shufflevector(eB1, eB1, 2, 3) };
      #pragma unroll
      for (int j = 0; j < 4; ++j) {
        A2[2*j][0]   = pk_fma_blo(ea[j], x0lo, A2[2*j][0]);
        A2[2*j][1]   = pk_fma_blo(ea[j], x0hi, A2[2*j][1]);
        A2[2*j+1][0] = pk_fma_bhi(ea[j], x0lo, A2[2*j+1][0]);
        A2[2*j+1][1] = pk_fma_bhi(ea[j], x0hi, A2[2*j+1][1]);
        A2[2*j][0]   = pk_fma_blo(eb[j], x1lo, A2[2*j][0]);
        A2[2*j][1]   = pk_fma_blo(eb[j], x1hi, A2[2*j][1]);
        A2[2*j+1][0] = pk_fma_bhi(eb[j], x1lo, A2[2*j+1][0]);
        A2[2*j+1][1] = pk_fma_bhi(eb[j], x1hi, A2[2*j+1][1]);
      }
    }
  }

  // ---- epilogue: cross-wave reduce + normalize (R5-verified)
  #pragma unroll
  for (int k = 0; k < 8; ++k) {
    float4 av;
    av.x = A2[k][0][0]; av.y = A2[k][0][1];
    av.z = A2[k][1][0]; av.w = A2[k][1][1];
    *reinterpret_cast<float4*>(&As[wv][k][4 * lane]) = av;
  }
  if (lane < 8) dws[wv][lane] = dacc;
  __syncthreads();
  if (t < 8) {
    float ds = dws[0][t] + dws[1][t] + dws[2][t] + dws[3][t];
    dinvs[t] = ds > 0.f ? 1.0f / ds : 0.f;
  }
  __syncthreads();
  #pragma unroll
  for (int r2 = 0; r2 < 8; ++r2) {
    float v = As[0][r2][t] + As[1][r2][t] + As[2][r2][t] + As[3][r2][t];
    Ag[(size_t)b * 2048 + r2 * 256 + t] = v * dinvs[r2];
  }
}

// ---------------- K5: att = A . Wv + bv (nonempty), out = att . Wo + bo
__global__ __launch_bounds__(256) void k_out(const float* __restrict__ Ag,
                                             const int* __restrict__ bounds,
                                             const float* __restrict__ Wv,
                                             const float* __restrict__ bv,
                                             const float* __restrict__ Wo,
                                             const float* __restrict__ bo,
                                             float* __restrict__ out) {
  __shared__ float Alds[4 * 2048];   // 32 KB
  __shared__ float attlds[4 * 256];  // 4 KB
  __shared__ float eflag[4];
  int b0 = blockIdx.x * 4;
  int t = threadIdx.x;
  #pragma unroll
  for (int r = 0; r < 32; ++r) {
    int idx = r * 256 + t;
    Alds[idx] = Ag[(size_t)b0 * 2048 + idx];
  }
  if (t < 4) {
    int s = bounds[2 * (b0 + t)], e = bounds[2 * (b0 + t) + 1];
    eflag[t] = (e > s) ? 1.0f : 0.0f;
  }
  __syncthreads();
  int h = t >> 5;
  float bvk = bv[t];
  float acc[4];
  #pragma unroll
  for (int g = 0; g < 4; ++g) acc[g] = 0.f;
  for (int i4 = 0; i4 < 64; ++i4) {
    float aa[4][4];
    #pragma unroll
    for (int g = 0; g < 4; ++g) {
      float4 v = *reinterpret_cast<const float4*>(&Alds[g * 2048 + h * 256 + i4 * 4]);
      aa[g][0] = v.x; aa[g][1] = v.y; aa[g][2] = v.z; aa[g][3] = v.w;
    }
    #pragma unroll
    for (int j = 0; j < 4; ++j) {
      float wvv = Wv[(size_t)(i4 * 4 + j) * 256 + t];
      #pragma unroll
      for (int g = 0; g < 4; ++g) acc[g] = fmaf(aa[g][j], wvv, acc[g]);
    }
  }
  #pragma unroll
  for (int g = 0; g < 4; ++g) attlds[g * 256 + t] = acc[g] + bvk * eflag[g];
  __syncthreads();
  float boj = bo[t];
  float o[4];
  #pragma unroll
  for (int g = 0; g < 4; ++g) o[g] = boj;
  for (int k4 = 0; k4 < 64; ++k4) {
    float aa[4][4];
    #pragma unroll
    for (int g = 0; g < 4; ++g) {
      float4 v = *reinterpret_cast<const float4*>(&attlds[g * 256 + k4 * 4]);
      aa[g][0] = v.x; aa[g][1] = v.y; aa[g][2] = v.z; aa[g][3] = v.w;
    }
    #pragma unroll
    for (int j = 0; j < 4; ++j) {
      float wo = Wo[(size_t)(k4 * 4 + j) * 256 + t];
      #pragma unroll
      for (int g = 0; g < 4; ++g) o[g] = fmaf(aa[g][j], wo, o[g]);
    }
  }
  #pragma unroll
  for (int g = 0; g < 4; ++g) out[(size_t)(b0 + g) * 256 + t] = o[g];
}

extern "C" void kernel_launch(void* const* d_in, const int* in_sizes, int n_in,
                              void* d_out, int out_size, void* d_ws, size_t ws_size,
                              hipStream_t stream) {
  const float* x   = (const float*)d_in[0];
  const int*   bat = (const int*)d_in[1];
  const float* q   = (const float*)d_in[2];
  const float* Wk  = (const float*)d_in[3];
  const float* bk  = (const float*)d_in[4];
  const float* Wv  = (const float*)d_in[5];
  const float* bv  = (const float*)d_in[6];
  const float* Wo  = (const float*)d_in[7];
  const float* bo  = (const float*)d_in[8];
  float* out = (float*)d_out;

  float* ws = (float*)d_ws;
  float*    P      = ws;                      // [0, 2048)
  float*    c      = ws + 2048;               // [2048, 2056)
  int*      bounds = (int*)(ws + 4096);       // [4096, 8192) as ints
  ushort_t* Pbf    = (ushort_t*)(ws + 8192);  // 2048 ushorts
  float*    Ag     = ws + 16384;              // 2048*2048 floats

  k_prep<<<8, 256, 0, stream>>>(Wk, bk, q, P, Pbf, c);
  k_bounds<<<8, 256, 0, stream>>>(bat, bounds);
  k_fused<<<NGRAPH, 256, 0, stream>>>(x, Pbf, c, bounds, Ag);
  k_out<<<NGRAPH / 4, 256, 0, stream>>>(Ag, bounds, Wv, bv, Wo, bo, out);
}

// Round 8
// 98.032 us; speedup vs baseline: 1.2706x; 1.2706x over previous
//
#include <hip/hip_runtime.h>

#define N_ATOMS 262144
#define NGRAPH  2048
#define INV_SCALE 0.17677669529663687f  // 1/sqrt(32)

typedef float f32x2 __attribute__((ext_vector_type(2)));
typedef float f32x4 __attribute__((ext_vector_type(4)));

// CDNA packed fp32 (VOP3P), R5-verified.
__device__ __forceinline__ f32x2 pk_mul(f32x2 a, f32x2 b) {
  f32x2 d; asm("v_pk_mul_f32 %0, %1, %2" : "=v"(d) : "v"(a), "v"(b)); return d;
}
__device__ __forceinline__ f32x2 pk_fma(f32x2 a, f32x2 b, f32x2 c) {
  f32x2 d; asm("v_pk_fma_f32 %0, %1, %2, %3" : "=v"(d) : "v"(a), "v"(b), "v"(c)); return d;
}
__device__ __forceinline__ f32x2 pk_fma_blo(f32x2 a, f32x2 b, f32x2 c) {
  f32x2 d; asm("v_pk_fma_f32 %0, %1, %2, %3 op_sel_hi:[0,1,1]"
               : "=v"(d) : "v"(a), "v"(b), "v"(c)); return d;
}
__device__ __forceinline__ f32x2 pk_fma_bhi(f32x2 a, f32x2 b, f32x2 c) {
  f32x2 d; asm("v_pk_fma_f32 %0, %1, %2, %3 op_sel:[1,0,0]"
               : "=v"(d) : "v"(a), "v"(b), "v"(c)); return d;
}
__device__ __forceinline__ f32x4 ldnt4(const float* p) {
  return __builtin_nontemporal_load(reinterpret_cast<const f32x4*>(p));
}

// ---------------- K1: fused prep (blocks 0-7) + bounds (blocks 8-15).
__global__ void k_pre(const float* __restrict__ Wk, const float* __restrict__ bk,
                      const float* __restrict__ q, const int* __restrict__ batch,
                      float* __restrict__ P, float* __restrict__ c,
                      int* __restrict__ bounds) {
  if (blockIdx.x < 8) {
    int h = blockIdx.x, i = threadIdx.x;
    float s = 0.f;
    #pragma unroll
    for (int d = 0; d < 32; ++d)
      s = fmaf(Wk[i * 256 + h * 32 + d], q[h * 32 + d], s);
    P[h * 256 + i] = s;
    if (i == 0) {
      float cc = 0.f;
      #pragma unroll
      for (int d = 0; d < 32; ++d) cc = fmaf(bk[h * 32 + d], q[h * 32 + d], cc);
      c[h] = cc;
    }
  } else {
    int g = (blockIdx.x - 8) * 256 + threadIdx.x;
    if (g >= NGRAPH) return;
    int lo = 0, hi = N_ATOMS;
    while (lo < hi) {
      int mid = (lo + hi) >> 1;
      if (batch[mid] < g) lo = mid + 1; else hi = mid;
    }
    bounds[2 * g] = lo;
    if (g > 0) bounds[2 * g - 1] = lo;
    if (g == NGRAPH - 1) bounds[2 * g + 1] = N_ATOMS;
  }
}

// transpose-reduce: 8 head-partials/lane over 64 lanes -> full dot of head h at
// every lane (head ownership h(lane) = bit-mix of lane bits 3,4,5). R2-verified.
__device__ __forceinline__ float fold8(float acc[8], int lane) {
  {
    int m = lane & 8;
    float nw[4];
    #pragma unroll
    for (int j = 0; j < 4; ++j) {
      float snd = m ? acc[j] : acc[j + 4];
      float rcv = __shfl_xor(snd, 8, 64);
      nw[j] = (m ? acc[j + 4] : acc[j]) + rcv;
    }
    #pragma unroll
    for (int j = 0; j < 4; ++j) acc[j] = nw[j];
  }
  {
    int m = lane & 16;
    float nw[2];
    #pragma unroll
    for (int j = 0; j < 2; ++j) {
      float snd = m ? acc[j] : acc[j + 2];
      float rcv = __shfl_xor(snd, 16, 64);
      nw[j] = (m ? acc[j + 2] : acc[j]) + rcv;
    }
    acc[0] = nw[0]; acc[1] = nw[1];
  }
  float r;
  {
    int m = lane & 32;
    float snd = m ? acc[0] : acc[1];
    float rcv = __shfl_xor(snd, 32, 64);
    r = (m ? acc[1] : acc[0]) + rcv;
  }
  r += __shfl_xor(r, 1, 64);
  r += __shfl_xor(r, 2, 64);
  r += __shfl_xor(r, 4, 64);
  return r;
}

// ---------------- K2: fused single-pass scores + exp + weighted accumulate.
// R5-verified math. One block per graph, 4 waves, 2 atoms/iter/wave, lane l =
// features 4l..4l+3 (coalesced 1KB/wave). LDS cut 34KB -> ~10KB (chunked
// epilogue) for occupancy; x loads non-temporal (read-once stream).
__global__ __launch_bounds__(256) void k_fused(const float* __restrict__ x,
                                               const float* __restrict__ P,
                                               const float* __restrict__ c,
                                               const int* __restrict__ bounds,
                                               float* __restrict__ Ag) {
  int b = blockIdx.x;
  int s = bounds[2 * b], e = bounds[2 * b + 1];
  int t = threadIdx.x, lane = t & 63, wv = t >> 6;
  int h = ((lane >> 1) & 4) | ((lane >> 3) & 2) | ((lane >> 5) & 1);

  f32x2 Pl2[8][2];
  #pragma unroll
  for (int k = 0; k < 8; ++k) {
    f32x4 pv = *reinterpret_cast<const f32x4*>(P + k * 256 + 4 * lane);
    Pl2[k][0] = __builtin_shufflevector(pv, pv, 0, 1);
    Pl2[k][1] = __builtin_shufflevector(pv, pv, 2, 3);
  }
  float cl = c[h];

  f32x2 A2[8][2];
  #pragma unroll
  for (int k = 0; k < 8; ++k) { A2[k][0] = (f32x2)0.f; A2[k][1] = (f32x2)0.f; }
  float dacc = 0.f;

  __shared__ float elds[4][2][8];   // wave-private e-table
  __shared__ float Asc[4][2][256];  // 8 KB chunked epilogue buffer
  __shared__ float dws[4][8];
  __shared__ float dinvs[8];

  for (int n0 = s + 2 * wv; n0 < e; n0 += 8) {
    bool has2 = (n0 + 1) < e;
    int n1 = has2 ? n0 + 1 : n0;
    f32x4 xq0 = ldnt4(x + (size_t)n0 * 256 + 4 * lane);
    f32x4 xq1 = ldnt4(x + (size_t)n1 * 256 + 4 * lane);
    f32x2 x0lo = __builtin_shufflevector(xq0, xq0, 0, 1);
    f32x2 x0hi = __builtin_shufflevector(xq0, xq0, 2, 3);
    f32x2 x1lo = __builtin_shufflevector(xq1, xq1, 0, 1);
    f32x2 x1hi = __builtin_shufflevector(xq1, xq1, 2, 3);

    float acc0[8], acc1[8];
    #pragma unroll
    for (int k = 0; k < 8; ++k) {
      f32x2 p0 = pk_fma(x0hi, Pl2[k][1], pk_mul(x0lo, Pl2[k][0]));
      f32x2 p1 = pk_fma(x1hi, Pl2[k][1], pk_mul(x1lo, Pl2[k][0]));
      acc0[k] = p0[0] + p0[1];
      acc1[k] = p1[0] + p1[1];
    }
    float r0 = fold8(acc0, lane);
    float r1 = fold8(acc1, lane);
    float ev0 = __expf((r0 + cl) * INV_SCALE);
    float ev1 = __expf((r1 + cl) * INV_SCALE);
    ev1 = has2 ? ev1 : 0.f;
    dacc += ev0 + ev1;

    if ((lane & 7) == 0) {
      elds[wv][0][h] = ev0;
      elds[wv][1][h] = ev1;
    }
    f32x4 ea03 = *reinterpret_cast<const f32x4*>(&elds[wv][0][0]);
    f32x4 ea47 = *reinterpret_cast<const f32x4*>(&elds[wv][0][4]);
    f32x4 eb03 = *reinterpret_cast<const f32x4*>(&elds[wv][1][0]);
    f32x4 eb47 = *reinterpret_cast<const f32x4*>(&elds[wv][1][4]);
    f32x2 ea[4] = { __builtin_shufflevector(ea03, ea03, 0, 1),
                    __builtin_shufflevector(ea03, ea03, 2, 3),
                    __builtin_shufflevector(ea47, ea47, 0, 1),
                    __builtin_shufflevector(ea47, ea47, 2, 3) };
    f32x2 eb[4] = { __builtin_shufflevector(eb03, eb03, 0, 1),
                    __builtin_shufflevector(eb03, eb03, 2, 3),
                    __builtin_shufflevector(eb47, eb47, 0, 1),
                    __builtin_shufflevector(eb47, eb47, 2, 3) };
    #pragma unroll
    for (int j = 0; j < 4; ++j) {
      A2[2*j][0]   = pk_fma_blo(ea[j], x0lo, A2[2*j][0]);
      A2[2*j][1]   = pk_fma_blo(ea[j], x0hi, A2[2*j][1]);
      A2[2*j+1][0] = pk_fma_bhi(ea[j], x0lo, A2[2*j+1][0]);
      A2[2*j+1][1] = pk_fma_bhi(ea[j], x0hi, A2[2*j+1][1]);
      A2[2*j][0]   = pk_fma_blo(eb[j], x1lo, A2[2*j][0]);
      A2[2*j][1]   = pk_fma_blo(eb[j], x1hi, A2[2*j][1]);
      A2[2*j+1][0] = pk_fma_bhi(eb[j], x1lo, A2[2*j+1][0]);
      A2[2*j+1][1] = pk_fma_bhi(eb[j], x1hi, A2[2*j+1][1]);
    }
  }

  // ---- epilogue: denom, then 4 head-pair passes of cross-wave reduce.
  if ((lane & 7) == 0) dws[wv][h] = dacc;
  __syncthreads();
  if (t < 8) {
    float ds = dws[0][t] + dws[1][t] + dws[2][t] + dws[3][t];
    dinvs[t] = ds > 0.f ? 1.0f / ds : 0.f;
  }
  #pragma unroll
  for (int p = 0; p < 4; ++p) {
    float4 a0, a1;
    a0.x = A2[2*p][0][0];   a0.y = A2[2*p][0][1];
    a0.z = A2[2*p][1][0];   a0.w = A2[2*p][1][1];
    a1.x = A2[2*p+1][0][0]; a1.y = A2[2*p+1][0][1];
    a1.z = A2[2*p+1][1][0]; a1.w = A2[2*p+1][1][1];
    *reinterpret_cast<float4*>(&Asc[wv][0][4 * lane]) = a0;
    *reinterpret_cast<float4*>(&Asc[wv][1][4 * lane]) = a1;
    __syncthreads();
    float v0 = Asc[0][0][t] + Asc[1][0][t] + Asc[2][0][t] + Asc[3][0][t];
    float v1 = Asc[0][1][t] + Asc[1][1][t] + Asc[2][1][t] + Asc[3][1][t];
    Ag[(size_t)b * 2048 + (2*p) * 256 + t]   = v0 * dinvs[2*p];
    Ag[(size_t)b * 2048 + (2*p+1) * 256 + t] = v1 * dinvs[2*p+1];
    __syncthreads();
  }
}

// ---------------- K5: att = A . Wv + bv (nonempty), out = att . Wo + bo
__global__ __launch_bounds__(256) void k_out(const float* __restrict__ Ag,
                                             const int* __restrict__ bounds,
                                             const float* __restrict__ Wv,
                                             const float* __restrict__ bv,
                                             const float* __restrict__ Wo,
                                             const float* __restrict__ bo,
                                             float* __restrict__ out) {
  __shared__ float Alds[4 * 2048];   // 32 KB
  __shared__ float attlds[4 * 256];  // 4 KB
  __shared__ float eflag[4];
  int b0 = blockIdx.x * 4;
  int t = threadIdx.x;
  #pragma unroll
  for (int r = 0; r < 32; ++r) {
    int idx = r * 256 + t;
    Alds[idx] = Ag[(size_t)b0 * 2048 + idx];
  }
  if (t < 4) {
    int s = bounds[2 * (b0 + t)], e = bounds[2 * (b0 + t) + 1];
    eflag[t] = (e > s) ? 1.0f : 0.0f;
  }
  __syncthreads();
  int h = t >> 5;
  float bvk = bv[t];
  float acc[4];
  #pragma unroll
  for (int g = 0; g < 4; ++g) acc[g] = 0.f;
  for (int i4 = 0; i4 < 64; ++i4) {
    float aa[4][4];
    #pragma unroll
    for (int g = 0; g < 4; ++g) {
      float4 v = *reinterpret_cast<const float4*>(&Alds[g * 2048 + h * 256 + i4 * 4]);
      aa[g][0] = v.x; aa[g][1] = v.y; aa[g][2] = v.z; aa[g][3] = v.w;
    }
    #pragma unroll
    for (int j = 0; j < 4; ++j) {
      float wvv = Wv[(size_t)(i4 * 4 + j) * 256 + t];
      #pragma unroll
      for (int g = 0; g < 4; ++g) acc[g] = fmaf(aa[g][j], wvv, acc[g]);
    }
  }
  #pragma unroll
  for (int g = 0; g < 4; ++g) attlds[g * 256 + t] = acc[g] + bvk * eflag[g];
  __syncthreads();
  float boj = bo[t];
  float o[4];
  #pragma unroll
  for (int g = 0; g < 4; ++g) o[g] = boj;
  for (int k4 = 0; k4 < 64; ++k4) {
    float aa[4][4];
    #pragma unroll
    for (int g = 0; g < 4; ++g) {
      float4 v = *reinterpret_cast<const float4*>(&attlds[g * 256 + k4 * 4]);
      aa[g][0] = v.x; aa[g][1] = v.y; aa[g][2] = v.z; aa[g][3] = v.w;
    }
    #pragma unroll
    for (int j = 0; j < 4; ++j) {
      float wo = Wo[(size_t)(k4 * 4 + j) * 256 + t];
      #pragma unroll
      for (int g = 0; g < 4; ++g) o[g] = fmaf(aa[g][j], wo, o[g]);
    }
  }
  #pragma unroll
  for (int g = 0; g < 4; ++g) out[(size_t)(b0 + g) * 256 + t] = o[g];
}

extern "C" void kernel_launch(void* const* d_in, const int* in_sizes, int n_in,
                              void* d_out, int out_size, void* d_ws, size_t ws_size,
                              hipStream_t stream) {
  const float* x   = (const float*)d_in[0];
  const int*   bat = (const int*)d_in[1];
  const float* q   = (const float*)d_in[2];
  const float* Wk  = (const float*)d_in[3];
  const float* bk  = (const float*)d_in[4];
  const float* Wv  = (const float*)d_in[5];
  const float* bv  = (const float*)d_in[6];
  const float* Wo  = (const float*)d_in[7];
  const float* bo  = (const float*)d_in[8];
  float* out = (float*)d_out;

  float* ws = (float*)d_ws;
  float* P      = ws;                 // 2048 floats
  float* c      = ws + 2048;          // 8 floats
  int*   bounds = (int*)(ws + 4096);  // 4096 ints
  float* Ag     = ws + 8192;          // 2048*2048 floats

  k_pre<<<16, 256, 0, stream>>>(Wk, bk, q, bat, P, c, bounds);
  k_fused<<<NGRAPH, 256, 0, stream>>>(x, P, c, bounds, Ag);
  k_out<<<NGRAPH / 4, 256, 0, stream>>>(Ag, bounds, Wv, bv, Wo, bo, out);
}